// Round 2
// baseline (2061.018 us; speedup 1.0000x reference)
//
#include <hip/hip_runtime.h>

// RGCN layer: out[i] = relu( x[i]@root + bias + sum_r mean_{j in N_r(i)} x[j]@W[r] )
// Strategy: aggregate-then-transform (aggregation is linear):
//   agg[r][dst] += x[src]  (scatter, atomics), cnt[r][dst] += 1
//   out = relu( x@root + bias + sum_r (agg[r]/max(cnt,1)) @ W[r] )   (fused 9-segment GEMM)

#define D 128   // D_IN == D_HID == 128

// ---------------------------------------------------------------------------
// Scatter: one edge handled by 32 consecutive threads (float4 per lane).
// ---------------------------------------------------------------------------
__global__ __launch_bounds__(256) void rgcn_scatter(
    const float* __restrict__ x,
    const int* __restrict__ edge_index,   // [2, E] : src row then dst row
    const int* __restrict__ edge_type,    // [E]
    float* __restrict__ agg,              // [rel_cnt][n_nodes][D]
    int* __restrict__ counts,             // [n_rel][n_nodes]  (absolute rel index)
    int n_nodes, int n_edges, int rel_base, int rel_cnt)
{
    long long t = (long long)blockIdx.x * blockDim.x + threadIdx.x;
    long long e = t >> 5;
    int lane = (int)(t & 31);
    if (e >= (long long)n_edges) return;

    int r = edge_type[e] - rel_base;
    if (r < 0 || r >= rel_cnt) return;

    int src = edge_index[e];
    int dst = edge_index[(long long)n_edges + e];

    float4 v = *(const float4*)(x + (size_t)src * D + lane * 4);
    float* p = agg + ((size_t)r * n_nodes + dst) * D + lane * 4;
    atomicAdd(p + 0, v.x);
    atomicAdd(p + 1, v.y);
    atomicAdd(p + 2, v.z);
    atomicAdd(p + 3, v.w);
    if (lane == 0) atomicAdd(counts + (size_t)(r + rel_base) * n_nodes + dst, 1);
}

// ---------------------------------------------------------------------------
// Fused GEMM over segments {root (if init)} ∪ {relations rel_base..+rel_cnt}.
// Block: 256 threads computes a 64-node x 128-col tile of out.
// Thread (tm = tid>>4, th = tid&15) computes rows tm*4..+3, cols th*8..+7.
// A tile staged in LDS (row-scaled by 1/cnt for relation segments).
// ---------------------------------------------------------------------------
__global__ __launch_bounds__(256) void rgcn_gemm(
    const float* __restrict__ x,          // [n_nodes][D]
    const float* __restrict__ agg,        // [rel_cnt][n_nodes][D]
    const int* __restrict__ counts,       // [n_rel][n_nodes]
    const float* __restrict__ W,          // [n_rel][D][D]
    const float* __restrict__ root,       // [D][D]
    const float* __restrict__ bias,       // [D]
    float* __restrict__ out,              // [n_nodes][D]
    int n_nodes, int rel_base, int rel_cnt, int init, int finalize)
{
    __shared__ float A[64][D + 4];        // +4 pad: keeps float4 align, breaks 4-way bank alias

    const int tid = threadIdx.x;
    const int m0 = blockIdx.x * 64;
    const int tm = tid >> 4;              // 0..15
    const int th = tid & 15;              // 0..15

    float acc[4][8];
#pragma unroll
    for (int j = 0; j < 4; ++j)
#pragma unroll
        for (int i = 0; i < 8; ++i) acc[j][i] = 0.f;

    const int nseg = rel_cnt + (init ? 1 : 0);
    for (int s = 0; s < nseg; ++s) {
        const bool is_root = (init && s == 0);
        const int rloc = s - (init ? 1 : 0);        // relation index within chunk
        const int rabs = rel_base + rloc;           // absolute relation index
        const float* srcbase = is_root ? x : (agg + (size_t)rloc * n_nodes * D);

        __syncthreads();   // protect previous tile's readers
#pragma unroll
        for (int i = 0; i < 8; ++i) {
            int idx = tid + i * 256;                // 0..2047
            int row = idx >> 5;
            int c4  = idx & 31;
            int node = m0 + row;
            float4 v = make_float4(0.f, 0.f, 0.f, 0.f);
            if (node < n_nodes) {
                v = *(const float4*)(srcbase + (size_t)node * D + c4 * 4);
                if (!is_root) {
                    int c = counts[(size_t)rabs * n_nodes + node];
                    if (c > 0) {
                        float sc = 1.f / (float)c;
                        v.x *= sc; v.y *= sc; v.z *= sc; v.w *= sc;
                    } else {
                        v = make_float4(0.f, 0.f, 0.f, 0.f);
                    }
                }
            }
            *(float4*)&A[row][c4 * 4] = v;
        }
        __syncthreads();

        const float* Wseg = is_root ? root : (W + (size_t)rabs * D * D);
#pragma unroll 4
        for (int k = 0; k < D; ++k) {
            float a0 = A[tm * 4 + 0][k];
            float a1 = A[tm * 4 + 1][k];
            float a2 = A[tm * 4 + 2][k];
            float a3 = A[tm * 4 + 3][k];
            float4 w0 = *(const float4*)(Wseg + (size_t)k * D + th * 8);
            float4 w1 = *(const float4*)(Wseg + (size_t)k * D + th * 8 + 4);
            float a[4] = {a0, a1, a2, a3};
            float w[8] = {w0.x, w0.y, w0.z, w0.w, w1.x, w1.y, w1.z, w1.w};
#pragma unroll
            for (int j = 0; j < 4; ++j)
#pragma unroll
                for (int i = 0; i < 8; ++i)
                    acc[j][i] += a[j] * w[i];
        }
    }

    // Epilogue
#pragma unroll
    for (int j = 0; j < 4; ++j) {
        int node = m0 + tm * 4 + j;
        if (node >= n_nodes) continue;
        float* op = out + (size_t)node * D + th * 8;
        float vals[8];
#pragma unroll
        for (int i = 0; i < 8; ++i) vals[i] = acc[j][i];
        if (init) {
#pragma unroll
            for (int i = 0; i < 8; ++i) vals[i] += bias[th * 8 + i];
        } else {
#pragma unroll
            for (int i = 0; i < 8; ++i) vals[i] += op[i];
        }
        if (finalize) {
#pragma unroll
            for (int i = 0; i < 8; ++i) vals[i] = fmaxf(vals[i], 0.f);
        }
        float4 o0 = make_float4(vals[0], vals[1], vals[2], vals[3]);
        float4 o1 = make_float4(vals[4], vals[5], vals[6], vals[7]);
        *(float4*)(op + 0) = o0;
        *(float4*)(op + 4) = o1;
    }
}

extern "C" void kernel_launch(void* const* d_in, const int* in_sizes, int n_in,
                              void* d_out, int out_size, void* d_ws, size_t ws_size,
                              hipStream_t stream) {
    const float* x          = (const float*)d_in[0];
    const int*   edge_index = (const int*)d_in[1];
    const int*   edge_type  = (const int*)d_in[2];
    const float* W          = (const float*)d_in[3];
    const float* root       = (const float*)d_in[4];
    const float* bias       = (const float*)d_in[5];
    float* out = (float*)d_out;

    const int n_nodes = in_sizes[0] / D;          // 100000
    const int n_edges = in_sizes[2];              // 600000
    const int n_rel   = in_sizes[3] / (D * D);    // 8

    // Workspace layout: [counts: n_rel*n_nodes ints][agg: chunk*n_nodes*D floats]
    int* counts = (int*)d_ws;
    size_t count_bytes = (size_t)n_rel * n_nodes * sizeof(int);
    size_t count_pad = (count_bytes + 255) & ~(size_t)255;
    float* agg = (float*)((char*)d_ws + count_pad);

    size_t per_rel = (size_t)n_nodes * D * sizeof(float);
    size_t avail = (ws_size > count_pad) ? (ws_size - count_pad) : 0;
    int chunk = (int)(avail / per_rel);
    if (chunk > n_rel) chunk = n_rel;
    if (chunk < 1) chunk = 1;                     // (would OOB only if ws is absurdly small)

    hipMemsetAsync(counts, 0, count_bytes, stream);

    const int scatter_block = 256;
    const long long scatter_threads = (long long)n_edges * 32;
    const int scatter_grid = (int)((scatter_threads + scatter_block - 1) / scatter_block);
    const int gemm_grid = (n_nodes + 63) / 64;

    for (int base = 0; base < n_rel; base += chunk) {
        int rc = n_rel - base; if (rc > chunk) rc = chunk;
        hipMemsetAsync(agg, 0, (size_t)rc * per_rel, stream);
        rgcn_scatter<<<scatter_grid, scatter_block, 0, stream>>>(
            x, edge_index, edge_type, agg, counts, n_nodes, n_edges, base, rc);
        int init = (base == 0) ? 1 : 0;
        int fin  = (base + rc >= n_rel) ? 1 : 0;
        rgcn_gemm<<<gemm_grid, 256, 0, stream>>>(
            x, agg, counts, W, root, bias, out, n_nodes, base, rc, init, fin);
    }
}

// Round 4
// 1055.649 us; speedup vs baseline: 1.9524x; 1.9524x over previous
//
#include <hip/hip_runtime.h>

// RGCN layer: out[i] = relu( x[i]@root + bias + sum_r mean_{j in N_r(i)} x[j]@W[r] )
//
// Fully fused tile strategy (no agg materialization, no memset/memcpy nodes —
// pure kernel chain so graph capture has only kernel nodes):
//   1. init_ints: zero (tile,rel) histogram
//   2. edge_hist: count edges per (dst-tile, rel) bin
//   3. scan_bins: exclusive prefix -> binptr[] AND cursor[] (in-place, no memcpy)
//   4. edge_bin:  scatter packed (src | dstlocal<<17) into bin-sorted order
//   5. rgcn_fused: per 64-node tile: for each segment (root, rel 0..7) build
//      64x128 A-tile in LDS (root: coalesced x load; rel: gather x[src] +
//      LDS atomic add over the bin's exact edge range + 1/cnt scale), then
//      register-tiled GEMM vs W[seg], accumulate; epilogue bias+relu.

#define D     128
#define TILE  64

// ---------------------------------------------------------------------------
__global__ __launch_bounds__(256) void init_ints(int* __restrict__ p, int n)
{
    int i = blockIdx.x * 256 + threadIdx.x;
    if (i < n) p[i] = 0;
}

// ---------------------------------------------------------------------------
__global__ __launch_bounds__(256) void edge_hist(
    const int* __restrict__ edge_index, const int* __restrict__ edge_type,
    int* __restrict__ hist, int n_edges, int n_rel)
{
    int e = blockIdx.x * 256 + threadIdx.x;
    if (e >= n_edges) return;
    int dst = edge_index[n_edges + e];
    int r   = edge_type[e];
    atomicAdd(&hist[(dst >> 6) * n_rel + r], 1);
}

// ---------------------------------------------------------------------------
// Exclusive scan of data[n] (in-place) and into ptr[n+1]. Single block.
// ---------------------------------------------------------------------------
__global__ __launch_bounds__(256) void scan_bins(
    int* __restrict__ data,   // in: hist; out: exclusive prefix (bin cursor)
    int* __restrict__ ptr,    // out: exclusive prefix, ptr[n] = total
    int n)
{
    __shared__ int buf[2][256];
    const int tid = threadIdx.x;
    int carry = 0;
    for (int c0 = 0; c0 < n; c0 += 256) {
        int i = c0 + tid;
        int v = (i < n) ? data[i] : 0;
        buf[0][tid] = v;
        __syncthreads();
        int pi = 0;
        for (int off = 1; off < 256; off <<= 1) {
            int t = buf[pi][tid] + ((tid >= off) ? buf[pi][tid - off] : 0);
            buf[1 - pi][tid] = t;
            pi = 1 - pi;
            __syncthreads();
        }
        int ex = carry + buf[pi][tid] - v;     // exclusive
        if (i < n) { ptr[i] = ex; data[i] = ex; }
        carry += buf[pi][255];
        __syncthreads();                       // protect buf before next chunk
    }
    if (tid == 0) ptr[n] = carry;
}

// ---------------------------------------------------------------------------
__global__ __launch_bounds__(256) void edge_bin(
    const int* __restrict__ edge_index, const int* __restrict__ edge_type,
    int* __restrict__ cursor, unsigned* __restrict__ packed, int n_edges, int n_rel)
{
    int e = blockIdx.x * 256 + threadIdx.x;
    if (e >= n_edges) return;
    int src = edge_index[e];
    int dst = edge_index[n_edges + e];
    int r   = edge_type[e];
    int pos = atomicAdd(&cursor[(dst >> 6) * n_rel + r], 1);
    packed[pos] = (unsigned)src | ((unsigned)(dst & 63) << 17);
}

// ---------------------------------------------------------------------------
// Fused aggregate+GEMM. Block = 256 threads = one 64-node tile.
// Thread (tm=tid>>4, th=tid&15) owns rows tm*4..+3, cols th*8..+7 of out.
// ---------------------------------------------------------------------------
__global__ __launch_bounds__(256) void rgcn_fused(
    const float* __restrict__ x,          // [n_nodes][D]
    const unsigned* __restrict__ packed,  // [n_edges] bin-sorted
    const int* __restrict__ binptr,       // [ntiles*n_rel + 1]
    const float* __restrict__ W,          // [n_rel][D][D]
    const float* __restrict__ root,       // [D][D]
    const float* __restrict__ bias,       // [D]
    float* __restrict__ out,              // [n_nodes][D]
    int n_nodes, int n_rel)
{
    __shared__ float A[TILE][D + 4];      // +4 pad: GEMM column reads 2-way (free)
    __shared__ int   cnt[TILE];
    __shared__ float inv[TILE];

    const int tid  = threadIdx.x;
    const int m0   = blockIdx.x * TILE;
    const int tm   = tid >> 4;
    const int th   = tid & 15;
    const int g    = tid >> 5;            // 32-lane group 0..7
    const int lane = tid & 31;

    float acc[4][8];
#pragma unroll
    for (int j = 0; j < 4; ++j)
#pragma unroll
        for (int i = 0; i < 8; ++i) acc[j][i] = 0.f;

    for (int s = 0; s <= n_rel; ++s) {
        __syncthreads();                  // protect previous A-tile readers
        if (s == 0) {
            // root segment: A = x rows (coalesced)
#pragma unroll
            for (int i = 0; i < 8; ++i) {
                int idx = tid + i * 256;
                int row = idx >> 5, c4 = idx & 31;
                int node = m0 + row;
                float4 v = make_float4(0.f, 0.f, 0.f, 0.f);
                if (node < n_nodes) v = *(const float4*)(x + (size_t)node * D + c4 * 4);
                *(float4*)&A[row][c4 * 4] = v;
            }
        } else {
            // zero tile + counts
#pragma unroll
            for (int i = 0; i < 8; ++i) {
                int idx = tid + i * 256;
                int row = idx >> 5, c4 = idx & 31;
                *(float4*)&A[row][c4 * 4] = make_float4(0.f, 0.f, 0.f, 0.f);
            }
            if (tid < TILE) cnt[tid] = 0;
            __syncthreads();

            // gather + LDS-atomic aggregate over this (tile, rel) bin's range
            const int r  = s - 1;
            const int e0 = binptr[blockIdx.x * n_rel + r];
            const int e1 = binptr[blockIdx.x * n_rel + r + 1];
            for (int e = e0 + g; e < e1; e += 8) {
                unsigned p = packed[e];
                int src = (int)(p & 0x1FFFF);
                int dl  = (int)((p >> 17) & 63);
                if (src < n_nodes) {
                    const float* xs = x + (size_t)src * D + lane;
                    // lane-contiguous columns: conflict-free LDS banks
                    atomicAdd(&A[dl][lane +  0], xs[ 0]);
                    atomicAdd(&A[dl][lane + 32], xs[32]);
                    atomicAdd(&A[dl][lane + 64], xs[64]);
                    atomicAdd(&A[dl][lane + 96], xs[96]);
                    if (lane == 0) atomicAdd(&cnt[dl], 1);
                }
            }
            __syncthreads();
            if (tid < TILE) inv[tid] = (cnt[tid] > 0) ? 1.f / (float)cnt[tid] : 0.f;
            __syncthreads();
            // scale rows by 1/cnt (mean)
#pragma unroll
            for (int i = 0; i < 8; ++i) {
                int idx = tid + i * 256;
                int row = idx >> 5, c4 = idx & 31;
                float sc = inv[row];
                float4 v = *(float4*)&A[row][c4 * 4];
                v.x *= sc; v.y *= sc; v.z *= sc; v.w *= sc;
                *(float4*)&A[row][c4 * 4] = v;
            }
        }
        __syncthreads();

        const float* Wseg = (s == 0) ? root : (W + (size_t)(s - 1) * D * D);
#pragma unroll 4
        for (int k = 0; k < D; ++k) {
            float a0 = A[tm * 4 + 0][k];
            float a1 = A[tm * 4 + 1][k];
            float a2 = A[tm * 4 + 2][k];
            float a3 = A[tm * 4 + 3][k];
            float4 w0 = *(const float4*)(Wseg + (size_t)k * D + th * 8);
            float4 w1 = *(const float4*)(Wseg + (size_t)k * D + th * 8 + 4);
            float a[4] = {a0, a1, a2, a3};
            float w[8] = {w0.x, w0.y, w0.z, w0.w, w1.x, w1.y, w1.z, w1.w};
#pragma unroll
            for (int j = 0; j < 4; ++j)
#pragma unroll
                for (int i = 0; i < 8; ++i)
                    acc[j][i] += a[j] * w[i];
        }
    }

    // epilogue: bias + relu + store
    float b[8];
#pragma unroll
    for (int i = 0; i < 8; ++i) b[i] = bias[th * 8 + i];
#pragma unroll
    for (int j = 0; j < 4; ++j) {
        int node = m0 + tm * 4 + j;
        if (node >= n_nodes) continue;
        float* op = out + (size_t)node * D + th * 8;
        float4 o0, o1;
        o0.x = fmaxf(acc[j][0] + b[0], 0.f);
        o0.y = fmaxf(acc[j][1] + b[1], 0.f);
        o0.z = fmaxf(acc[j][2] + b[2], 0.f);
        o0.w = fmaxf(acc[j][3] + b[3], 0.f);
        o1.x = fmaxf(acc[j][4] + b[4], 0.f);
        o1.y = fmaxf(acc[j][5] + b[5], 0.f);
        o1.z = fmaxf(acc[j][6] + b[6], 0.f);
        o1.w = fmaxf(acc[j][7] + b[7], 0.f);
        *(float4*)(op + 0) = o0;
        *(float4*)(op + 4) = o1;
    }
}

extern "C" void kernel_launch(void* const* d_in, const int* in_sizes, int n_in,
                              void* d_out, int out_size, void* d_ws, size_t ws_size,
                              hipStream_t stream) {
    const float* x          = (const float*)d_in[0];
    const int*   edge_index = (const int*)d_in[1];
    const int*   edge_type  = (const int*)d_in[2];
    const float* W          = (const float*)d_in[3];
    const float* root       = (const float*)d_in[4];
    const float* bias       = (const float*)d_in[5];
    float* out = (float*)d_out;

    const int n_nodes = in_sizes[0] / D;          // 100000
    const int n_edges = in_sizes[2];              // 600000
    const int n_rel   = in_sizes[3] / (D * D);    // 8
    const int ntiles  = (n_nodes + TILE - 1) / TILE;
    const int nbins   = ntiles * n_rel;

    // ws layout: binptr[nbins+1 pad] | cursor[nbins pad] | packed[n_edges]
    int* binptr = (int*)d_ws;
    int* cursor = binptr + ((nbins + 1 + 63) & ~63);
    unsigned* packed = (unsigned*)(cursor + ((nbins + 63) & ~63));

    const int egrid = (n_edges + 255) / 256;
    const int bgrid = (nbins + 255) / 256;

    init_ints<<<bgrid, 256, 0, stream>>>(cursor, nbins);
    edge_hist<<<egrid, 256, 0, stream>>>(edge_index, edge_type, cursor, n_edges, n_rel);
    scan_bins<<<1, 256, 0, stream>>>(cursor, binptr, nbins);
    edge_bin<<<egrid, 256, 0, stream>>>(edge_index, edge_type, cursor, packed, n_edges, n_rel);
    rgcn_fused<<<ntiles, 256, 0, stream>>>(
        x, packed, binptr, W, root, bias, out, n_nodes, n_rel);
}

// Round 5
// 828.437 us; speedup vs baseline: 2.4878x; 1.2743x over previous
//
#include <hip/hip_runtime.h>

// RGCN layer: out[i] = relu( x[i]@root + bias + sum_r mean_{j in N_r(i)} x[j]@W[r] )
//
// Fused tile strategy, MFMA core:
//   prep_wt:   WT[seg][n][k] = bf16(Wseg[k][n])  (seg0=root, seg 1..8 = W[r])
//   init/hist/scan/bin: edges binned by (dst-tile, rel), packed = src | dl<<26
//   rgcn_fused: per 64-node tile: for each segment build 64x128 f32 A-tile in
//     LDS (root: coalesced load; rel: gather x[src] + LDS f32 atomics + 1/cnt
//     scale), convert per-wave to bf16 MFMA A-frags, multiply vs WT B-frags
//     (16x16x32 bf16 MFMA), accumulate across segments; epilogue bias+relu.

#define D     128
#define TILE  64

typedef __attribute__((ext_vector_type(8))) short  bf16x8;
typedef __attribute__((ext_vector_type(4))) float  f32x4;

__device__ inline unsigned short f32_to_bf16(float f) {
    unsigned u = __float_as_uint(f);
    return (unsigned short)((u + 0x7FFF + ((u >> 16) & 1)) >> 16);   // RNE
}

// ---------------------------------------------------------------------------
__global__ __launch_bounds__(256) void init_ints(int* __restrict__ p, int n)
{
    int i = blockIdx.x * 256 + threadIdx.x;
    if (i < n) p[i] = 0;
}

// ---------------------------------------------------------------------------
// WT[seg][n][k] = bf16( seg==0 ? root[k][n] : W[seg-1][k][n] )
// ---------------------------------------------------------------------------
__global__ __launch_bounds__(256) void prep_wt(
    const float* __restrict__ W, const float* __restrict__ root,
    unsigned short* __restrict__ WT, int n_rel)
{
    int idx = blockIdx.x * 256 + threadIdx.x;
    int total = (n_rel + 1) * D * D;
    if (idx >= total) return;
    int seg = idx >> 14;              // / (128*128)
    int rem = idx & 16383;
    int n = rem >> 7, k = rem & 127;
    float v = (seg == 0) ? root[k * D + n] : W[(size_t)(seg - 1) * D * D + k * D + n];
    WT[idx] = f32_to_bf16(v);
}

// ---------------------------------------------------------------------------
__global__ __launch_bounds__(256) void edge_hist(
    const int* __restrict__ edge_index, const int* __restrict__ edge_type,
    int* __restrict__ hist, int n_edges, int n_rel)
{
    int e = blockIdx.x * 256 + threadIdx.x;
    if (e >= n_edges) return;
    int dst = edge_index[n_edges + e];
    int r   = edge_type[e];
    atomicAdd(&hist[(dst >> 6) * n_rel + r], 1);
}

// ---------------------------------------------------------------------------
// Exclusive scan of data[n] (in-place, becomes cursor) and into ptr[n+1].
// ---------------------------------------------------------------------------
__global__ __launch_bounds__(256) void scan_bins(
    int* __restrict__ data, int* __restrict__ ptr, int n)
{
    __shared__ int buf[2][256];
    const int tid = threadIdx.x;
    int carry = 0;
    for (int c0 = 0; c0 < n; c0 += 256) {
        int i = c0 + tid;
        int v = (i < n) ? data[i] : 0;
        buf[0][tid] = v;
        __syncthreads();
        int pi = 0;
        for (int off = 1; off < 256; off <<= 1) {
            int t = buf[pi][tid] + ((tid >= off) ? buf[pi][tid - off] : 0);
            buf[1 - pi][tid] = t;
            pi = 1 - pi;
            __syncthreads();
        }
        int ex = carry + buf[pi][tid] - v;
        if (i < n) { ptr[i] = ex; data[i] = ex; }
        carry += buf[pi][255];
        __syncthreads();
    }
    if (tid == 0) ptr[n] = carry;
}

// ---------------------------------------------------------------------------
__global__ __launch_bounds__(256) void edge_bin(
    const int* __restrict__ edge_index, const int* __restrict__ edge_type,
    int* __restrict__ cursor, unsigned* __restrict__ packed, int n_edges, int n_rel)
{
    int e = blockIdx.x * 256 + threadIdx.x;
    if (e >= n_edges) return;
    int src = edge_index[e];
    int dst = edge_index[n_edges + e];
    int r   = edge_type[e];
    int pos = atomicAdd(&cursor[(dst >> 6) * n_rel + r], 1);
    packed[pos] = (unsigned)src | ((unsigned)(dst & 63) << 26);
}

// ---------------------------------------------------------------------------
// Fused aggregate + MFMA GEMM. Block = 256 threads (4 waves) = one 64-node
// tile. Wave w computes rows w*16..+15, all 128 cols, via 16x16x32 bf16 MFMA.
// ---------------------------------------------------------------------------
__global__ __launch_bounds__(256) void rgcn_fused(
    const float* __restrict__ x,             // [n_nodes][D]
    const unsigned* __restrict__ packed,     // [n_edges] bin-sorted
    const int* __restrict__ binptr,          // [ntiles*n_rel + 1]
    const unsigned short* __restrict__ WT,   // [n_rel+1][D][D] bf16, n-major
    const float* __restrict__ bias,          // [D]
    float* __restrict__ out,                 // [n_nodes][D]
    int n_nodes, int n_rel)
{
    __shared__ float A[TILE][D + 4];
    __shared__ int   cnt[TILE];
    __shared__ float inv[TILE];

    const int tid  = threadIdx.x;
    const int m0   = blockIdx.x * TILE;
    const int wave = tid >> 6;
    const int lane = tid & 63;
    const int l16  = lane & 15;
    const int quad = lane >> 4;

    f32x4 acc[8];
#pragma unroll
    for (int nt = 0; nt < 8; ++nt) acc[nt] = (f32x4){0.f, 0.f, 0.f, 0.f};

    for (int s = 0; s <= n_rel; ++s) {
        int e0 = 0, e1 = 0;
        if (s > 0) {
            e0 = binptr[blockIdx.x * n_rel + (s - 1)];
            e1 = binptr[blockIdx.x * n_rel + s];
            if (e0 == e1) continue;          // empty bin: A would be all-zero
        }

        __syncthreads();                     // prev segment's frag readers done
        if (s == 0) {
            // root segment: A = x rows (coalesced float4)
#pragma unroll
            for (int i = 0; i < 8; ++i) {
                int idx = tid + i * 256;
                int row = idx >> 5, c4 = idx & 31;
                int node = m0 + row;
                float4 v = make_float4(0.f, 0.f, 0.f, 0.f);
                if (node < n_nodes) v = *(const float4*)(x + (size_t)node * D + c4 * 4);
                *(float4*)&A[row][c4 * 4] = v;
            }
            __syncthreads();
        } else {
            // zero tile + counts
#pragma unroll
            for (int i = 0; i < 8; ++i) {
                int idx = tid + i * 256;
                int row = idx >> 5, c4 = idx & 31;
                *(float4*)&A[row][c4 * 4] = make_float4(0.f, 0.f, 0.f, 0.f);
            }
            if (tid < TILE) cnt[tid] = 0;
            __syncthreads();

            // gather + LDS f32 atomics: one edge per 64-lane wave
            for (int e = e0 + wave; e < e1; e += 4) {
                unsigned p = packed[e];
                int src = (int)(p & 0x03FFFFFF);
                int dl  = (int)(p >> 26);
                const float* xs = x + (size_t)src * D;
                atomicAdd(&A[dl][lane],      xs[lane]);
                atomicAdd(&A[dl][lane + 64], xs[lane + 64]);
                if (lane == 0) atomicAdd(&cnt[dl], 1);
            }
            __syncthreads();
            if (tid < TILE) inv[tid] = (cnt[tid] > 0) ? 1.f / (float)cnt[tid] : 0.f;
            __syncthreads();
            // scale rows by 1/cnt (mean)
#pragma unroll
            for (int i = 0; i < 8; ++i) {
                int idx = tid + i * 256;
                int row = idx >> 5, c4 = idx & 31;
                float sc = inv[row];
                float4 v = *(float4*)&A[row][c4 * 4];
                v.x *= sc; v.y *= sc; v.z *= sc; v.w *= sc;
                *(float4*)&A[row][c4 * 4] = v;
            }
            __syncthreads();
        }

        // A-frags: wave's rows = wave*16 + l16; k-chunk kc: k = kc*32 + quad*8 + j
        bf16x8 af[4];
        {
            const int m = wave * 16 + l16;
#pragma unroll
            for (int kc = 0; kc < 4; ++kc) {
                const float* ap = &A[m][kc * 32 + quad * 8];
                f32x4 lo = *(const f32x4*)ap;
                f32x4 hi = *(const f32x4*)(ap + 4);
                bf16x8 f;
                f[0] = (short)f32_to_bf16(lo[0]);
                f[1] = (short)f32_to_bf16(lo[1]);
                f[2] = (short)f32_to_bf16(lo[2]);
                f[3] = (short)f32_to_bf16(lo[3]);
                f[4] = (short)f32_to_bf16(hi[0]);
                f[5] = (short)f32_to_bf16(hi[1]);
                f[6] = (short)f32_to_bf16(hi[2]);
                f[7] = (short)f32_to_bf16(hi[3]);
                af[kc] = f;
            }
        }
        // NOTE: loop-top __syncthreads() protects A until all waves read frags.

        // B-frags from WT (L1/L2-hot): B[k][n], lane n = nt*16+l16, k = kc*32+quad*8+j
        const unsigned short* Wseg = WT + (size_t)s * D * D;
#pragma unroll
        for (int nt = 0; nt < 8; ++nt) {
            const unsigned short* bp = Wseg + (size_t)(nt * 16 + l16) * D + quad * 8;
#pragma unroll
            for (int kc = 0; kc < 4; ++kc) {
                bf16x8 bf = *(const bf16x8*)(bp + kc * 32);
                acc[nt] = __builtin_amdgcn_mfma_f32_16x16x32_bf16(af[kc], bf, acc[nt], 0, 0, 0);
            }
        }
    }

    // epilogue: bias + relu + store. C/D layout: col=l16 (+nt*16), row=quad*4+reg
#pragma unroll
    for (int nt = 0; nt < 8; ++nt) {
        int col = nt * 16 + l16;
        float bv = bias[col];
#pragma unroll
        for (int reg = 0; reg < 4; ++reg) {
            int node = m0 + wave * 16 + quad * 4 + reg;
            if (node < n_nodes)
                out[(size_t)node * D + col] = fmaxf(acc[nt][reg] + bv, 0.f);
        }
    }
}

extern "C" void kernel_launch(void* const* d_in, const int* in_sizes, int n_in,
                              void* d_out, int out_size, void* d_ws, size_t ws_size,
                              hipStream_t stream) {
    const float* x          = (const float*)d_in[0];
    const int*   edge_index = (const int*)d_in[1];
    const int*   edge_type  = (const int*)d_in[2];
    const float* W          = (const float*)d_in[3];
    const float* root       = (const float*)d_in[4];
    const float* bias       = (const float*)d_in[5];
    float* out = (float*)d_out;

    const int n_nodes = in_sizes[0] / D;          // 100000
    const int n_edges = in_sizes[2];              // 600000
    const int n_rel   = in_sizes[3] / (D * D);    // 8
    const int ntiles  = (n_nodes + TILE - 1) / TILE;
    const int nbins   = ntiles * n_rel;

    // ws layout: binptr[nbins+1] | cursor[nbins] | WT[(n_rel+1)*D*D bf16] | packed[n_edges]
    int* binptr = (int*)d_ws;
    int* cursor = binptr + ((nbins + 1 + 63) & ~63);
    unsigned short* WT = (unsigned short*)(cursor + ((nbins + 63) & ~63));
    size_t wt_elems = (size_t)(n_rel + 1) * D * D;
    unsigned* packed = (unsigned*)(WT + ((wt_elems + 127) & ~(size_t)127));

    const int egrid = (n_edges + 255) / 256;
    const int bgrid = (nbins + 255) / 256;
    const int wgrid = (int)((wt_elems + 255) / 256);

    init_ints<<<bgrid, 256, 0, stream>>>(cursor, nbins);
    prep_wt<<<wgrid, 256, 0, stream>>>(W, root, WT, n_rel);
    edge_hist<<<egrid, 256, 0, stream>>>(edge_index, edge_type, cursor, n_edges, n_rel);
    scan_bins<<<1, 256, 0, stream>>>(cursor, binptr, nbins);
    edge_bin<<<egrid, 256, 0, stream>>>(edge_index, edge_type, cursor, packed, n_edges, n_rel);
    rgcn_fused<<<ntiles, 256, 0, stream>>>(
        x, packed, binptr, WT, bias, out, n_nodes, n_rel);
}